// Round 12
// baseline (230.080 us; speedup 1.0000x reference)
//
#include <hip/hip_runtime.h>
#include <math.h>

#define B 8
#define V 1024
#define E 32
#define H 4
#define CAP 64        // max out-degree capacity; E[deg]=17, P(deg>64) ~ 1e-21
#define MAXNNZ 20480  // nnz ~ 17390 +/- 128; +24 sigma headroom
#define SE (MAXNNZ / V)  // 20 edges per thread in flow kernel
#define NBLK 512
#define NTHR 256

// XCD-aware decode: blockIdx round-robins across 8 XCDs on MI355X, and B==8.
// b = blk & 7 pins each batch's work to one XCD where it matters.

__device__ __forceinline__ float wave_sum(float v) {
  for (int o = 32; o > 0; o >>= 1) v += __shfl_xor(v, o);
  return v;
}
__device__ __forceinline__ float wave_max(float v) {
  for (int o = 32; o > 0; o >>= 1) v = fmaxf(v, __shfl_xor(v, o));
  return v;
}

struct Params {
  const float *adj, *demands, *emb;
  const float *ew1, *eb1, *ew2, *eb2, *dec_w2;
  const float *gat_w, *ga1, *ga2, *gate_w, *gate_u, *gate_b;
  const float *dw1, *db1, *uw1, *ub1, *uw2, *ub2, *dec_b2;
  int *nbr, *deg, *deg_in, *slot_cur, *csc_pos;
  float *fwe;
  unsigned *meta;
  float *w2t, *wa1, *wa2, *encA, *encB, *ssA, *snA, *ssB, *snB, *dvp, *rssq;
};

// ---- L0: zero counters + precompute wa1/wa2 = gat_w @ a1/a2 ----
__global__ void init_kernel(int* __restrict__ deg_in, int* __restrict__ slot_cur,
                            unsigned* __restrict__ done, const float* __restrict__ gat_w,
                            const float* __restrict__ a1, const float* __restrict__ a2,
                            float* __restrict__ wa1, float* __restrict__ wa2) {
  int blk = blockIdx.x, tid = threadIdx.x;
  if (blk < 4) {
    deg_in[blk * 256 + tid] = 0;
  } else if (blk < 8) {
    slot_cur[(blk - 4) * 256 + tid] = 0;
  } else {
    if (tid == 0) *done = 0u;
    int h = tid >> 6, f = tid & 63;
    float s1 = 0.f, s2 = 0.f;
    const float* W = gat_w + h * 4096 + f * 64;
    for (int g = 0; g < 64; ++g) {
      float w = W[g];
      s1 += w * a1[h * 64 + g];
      s2 += w * a2[h * 64 + g];
    }
    wa1[h * 64 + f] = s1;
    wa2[h * 64 + f] = s2;
  }
}

// ---- L1: CSR+indeg | encoder+L1 scores | w2t | zero fwe/meta ----
__global__ __launch_bounds__(NTHR) void p0_kernel(Params p) {
  __shared__ float arena[3104];
  int blk = blockIdx.x, tid = threadIdx.x, wid = tid >> 6, lane = tid & 63;
  if (blk < 128) {
    // CSR build (row-coalesced ballot compaction) + atomic kept-edge in-degree
    for (int rr = 0; rr < 2; ++rr) {
      int v = blk * 8 + wid * 2 + rr;
      int base = 0;
      for (int c = 0; c < V; c += 64) {
        float a = p.adj[(size_t)v * V + c + lane];
        unsigned long long m = __ballot(a > 0.5f);
        int pos = __popcll(m & ((1ull << lane) - 1ull));
        if (a > 0.5f && base + pos < CAP) {
          p.nbr[v * CAP + base + pos] = c + lane;
          atomicAdd(&p.deg_in[c + lane], 1);
        }
        base += __popcll(m);
      }
      if (lane == 0) p.deg[v] = (base < CAP) ? base : CAP;
    }
  } else if (blk < 256) {
    // encoder MLP (2 units of 8 nodes per wave) + layer-1 attention scores
    int bb = blk - 128;
    float wa1r[4], wa2r[4];
#pragma unroll
    for (int h = 0; h < 4; ++h) {
      wa1r[h] = p.wa1[h * 64 + lane];
      wa2r[h] = p.wa2[h * 64 + lane];
    }
    float* xs = arena + wid * 264;          // [8][33] per wave
    float* hsw = arena + 1056 + wid * 512;  // [8][64] per wave
    for (int uu = 0; uu < 2; ++uu) {
      int unit = (bb >> 3) * 64 + (wid * 2 + uu) * 8 + (bb & 7);
      int b = unit & 7, v0 = (unit >> 3) * 8, bv0 = b * V + v0;
#pragma unroll
      for (int n = 0; n < 8; ++n) {
        if (lane < E) xs[n * 33 + lane] = p.emb[(v0 + n) * E + lane];
        else if (lane == E) xs[n * 33 + E] = p.demands[b * V + v0 + n];
      }
      float h8[8];
#pragma unroll
      for (int n = 0; n < 8; ++n) h8[n] = p.eb1[lane];
      for (int i = 0; i < E + 1; ++i) {
        float wv = p.ew1[i * 64 + lane];
#pragma unroll
        for (int n = 0; n < 8; ++n) h8[n] += xs[n * 33 + i] * wv;
      }
#pragma unroll
      for (int n = 0; n < 8; ++n) hsw[n * 64 + lane] = fmaxf(h8[n], 0.f);
      float o8[8];
#pragma unroll
      for (int n = 0; n < 8; ++n) o8[n] = p.eb2[lane];
      for (int i = 0; i < 64; ++i) {
        float wv = p.ew2[i * 64 + lane];
#pragma unroll
        for (int n = 0; n < 8; ++n) o8[n] += hsw[n * 64 + i] * wv;
      }
#pragma unroll
      for (int n = 0; n < 8; ++n) {
        o8[n] = fmaxf(o8[n], 0.f);
        p.encA[(size_t)(bv0 + n) * 64 + lane] = o8[n];
      }
#pragma unroll
      for (int n = 0; n < 8; ++n) {
#pragma unroll
        for (int hh = 0; hh < 4; ++hh) {
          float v1 = wave_sum(o8[n] * wa1r[hh]);
          float v2 = wave_sum(o8[n] * wa2r[hh]);
          if (lane == 0) {
            p.ssA[(b * 4 + hh) * V + v0 + n] = v1;
            p.snA[(b * 4 + hh) * V + v0 + n] = v2;
          }
        }
      }
    }
  } else if (blk < 384) {
    for (int rr = 0; rr < 2; ++rr) {
      int col = (blk - 256) * 8 + wid * 2 + rr;
      p.w2t[col * 64 + lane] = p.dec_w2[(size_t)lane * V + col];
    }
  } else {
    // zero fwe + meta so pad slots are exactly 0 each launch
    int idx = (blk - 384) * 256 + tid;
    for (int i = idx; i < B * MAXNNZ; i += 128 * 256) p.fwe[i] = 0.f;
    for (int i = idx; i < MAXNNZ; i += 128 * 256) p.meta[i] = 0u;
  }
}

// ---- GAT layer pass (aggregate-then-project, no t materialization) ----
__device__ static void gat2_pass(const Params& p, const float* __restrict__ enc_in,
                                 const float* __restrict__ ss_in, const float* __restrict__ sn_in,
                                 float* __restrict__ enc_out, float* __restrict__ ss_out,
                                 float* __restrict__ sn_out, int write_s, int unit,
                                 float* arena) {
  int tid = threadIdx.x, wid = tid >> 6, lane = tid & 63;
  int b = unit & 7, v0 = (unit >> 3) * 8;
  float* agg = arena;            // [8][4][64]
  float* gpart = arena + 2048;   // [8][4][64]
  float* nxts = arena + 4096;    // [8][64]
  float* encs = arena + 4608;    // [8][64]
  const float* eb = enc_in + (size_t)b * V * 64;
  __syncthreads();  // protect LDS from previous pass
  for (int i = tid; i < 512; i += 256) encs[i] = eb[v0 * 64 + i];
  for (int n = wid; n < 8; n += 4) {
    int v = v0 + n;
    int dvv = p.deg[v];
    int wk = (lane < dvv) ? p.nbr[v * CAP + lane] : 0;
    float cc[4];
#pragma unroll
    for (int h = 0; h < 4; ++h) {
      float x = ss_in[(b * 4 + h) * V + v] + sn_in[(b * 4 + h) * V + wk];
      x = (x > 0.f) ? x : 0.2f * x;  // leaky_relu 0.2
      if (lane >= dvv) x = -1e30f;
      float m = wave_max(x);
      float e = (lane < dvv) ? __expf(x - m) : 0.f;
      float s = wave_sum(e);
      cc[h] = e / s;
    }
    float a0 = 0.f, a1 = 0.f, a2 = 0.f, a3 = 0.f;
    for (int k = 0; k < dvv; ++k) {
      int w = __shfl(wk, k);
      float ev = eb[w * 64 + lane];  // one 256B gather serves all 4 heads
      a0 += __shfl(cc[0], k) * ev;
      a1 += __shfl(cc[1], k) * ev;
      a2 += __shfl(cc[2], k) * ev;
      a3 += __shfl(cc[3], k) * ev;
    }
    agg[(n * 4 + 0) * 64 + lane] = a0;
    agg[(n * 4 + 1) * 64 + lane] = a1;
    agg[(n * 4 + 2) * 64 + lane] = a2;
    agg[(n * 4 + 3) * 64 + lane] = a3;
  }
  __syncthreads();
  {
    const float* W = p.gat_w + wid * 4096;
    float hv[8];
#pragma unroll
    for (int n = 0; n < 8; ++n) hv[n] = 0.f;
    for (int f = 0; f < 64; ++f) {
      float wf = W[f * 64 + lane];
#pragma unroll
      for (int n = 0; n < 8; ++n) hv[n] += agg[(n * 4 + wid) * 64 + f] * wf;
    }
#pragma unroll
    for (int n = 0; n < 8; ++n) gpart[(n * 4 + wid) * 64 + lane] = hv[n];
  }
  __syncthreads();
  for (int i = tid; i < 512; i += 256) {
    int n = i >> 6, g = i & 63;
    float s4 = gpart[(n * 4) * 64 + g] + gpart[(n * 4 + 1) * 64 + g] +
               gpart[(n * 4 + 2) * 64 + g] + gpart[(n * 4 + 3) * 64 + g];
    nxts[i] = fmaxf(0.25f * s4, 0.f);
  }
  __syncthreads();
  {
    float part[8];
#pragma unroll
    for (int n = 0; n < 8; ++n) part[n] = 0.f;
    for (int f = wid * 16; f < wid * 16 + 16; ++f) {
      float gw = p.gate_w[f * 64 + lane], gu = p.gate_u[f * 64 + lane];
#pragma unroll
      for (int n = 0; n < 8; ++n) part[n] += nxts[n * 64 + f] * gw + encs[n * 64 + f] * gu;
    }
    __syncthreads();
#pragma unroll
    for (int n = 0; n < 8; ++n) gpart[(n * 4 + wid) * 64 + lane] = part[n];
  }
  __syncthreads();
  for (int i = tid; i < 512; i += 256) {
    int n = i >> 6, g = i & 63;
    float zs = gpart[(n * 4) * 64 + g] + gpart[(n * 4 + 1) * 64 + g] +
               gpart[(n * 4 + 2) * 64 + g] + gpart[(n * 4 + 3) * 64 + g] + p.gate_b[g];
    float z = 1.f / (1.f + __expf(-zs));
    float out = z * nxts[i] + (1.f - z) * encs[i];
    encs[i] = out;
    enc_out[((size_t)b * V + v0 + n) * 64 + g] = out;
  }
  if (write_s) {
    __syncthreads();
    float w1v = p.wa1[wid * 64 + lane], w2v = p.wa2[wid * 64 + lane];
#pragma unroll
    for (int n = 0; n < 8; ++n) {
      float e2 = encs[n * 64 + lane];
      float ssv = wave_sum(e2 * w1v);
      float snv = wave_sum(e2 * w2v);
      if (lane == 0) {
        ss_out[(b * 4 + wid) * V + v0 + n] = ssv;
        sn_out[(b * 4 + wid) * V + v0 + n] = snv;
      }
    }
  }
}

// ---- L2: gat2 layer 1 (2 passes/block) + CSC slot assignment ----
__global__ __launch_bounds__(NTHR) void p1_kernel(Params p) {
  __shared__ float arena[6144];
  int blk = blockIdx.x, tid = threadIdx.x, wid = tid >> 6, lane = tid & 63;
  for (int ps = 0; ps < 2; ++ps) {
    int unit = ((blk >> 3) * 2 + ps) * 8 + (blk & 7);
    gat2_pass(p, p.encA, p.ssA, p.snA, p.encB, p.ssB, p.snB, 1, unit, arena);
  }
  __syncthreads();
  int* ioff = (int*)(arena + 5120);  // [V], disjoint from gat2 live region
  if (tid < 64) {  // redundant per-block exclusive scan of pristine deg_in
    int vals[16];
    int tot = 0;
#pragma unroll
    for (int i = 0; i < 16; ++i) {
      vals[i] = tot;
      tot += p.deg_in[tid * 16 + i];
    }
    int run = tot;
    for (int o = 1; o < 64; o <<= 1) {
      int u = __shfl_up(run, o);
      if (lane >= o) run += u;
    }
    int excl = run - tot;
#pragma unroll
    for (int i = 0; i < 16; ++i) ioff[tid * 16 + i] = excl + vals[i];
  }
  __syncthreads();
  if (wid < 2) {
    int v = blk * 2 + wid;
    if (lane < p.deg[v]) {
      int w = p.nbr[v * CAP + lane];
      p.csc_pos[v * CAP + lane] = ioff[w] + atomicAdd(&p.slot_cur[w], 1);
    }
  }
}

// ---- L3: gat2 layer 2 ----
__global__ __launch_bounds__(NTHR) void p2_kernel(Params p) {
  __shared__ float arena[6144];
  int blk = blockIdx.x;
  for (int ps = 0; ps < 2; ++ps) {
    int unit = ((blk >> 3) * 2 + ps) * 8 + (blk & 7);
    gat2_pass(p, p.encB, p.ssB, p.snB, p.encA, p.ssA, p.snA, 0, unit, arena);
  }
}

// ---- L4: decoder hidden + dual scalar + flow-weight softmax (lane-per-edge) ----
__global__ __launch_bounds__(NTHR) void p3_kernel(Params p) {
  __shared__ float arena[2048];
  int blk = blockIdx.x, tid = threadIdx.x, wid = tid >> 6, lane = tid & 63;
  int b = blk & 7, v0 = (blk >> 3) * 16 + wid * 4;
  int bv0 = b * V + v0;
  float* es = arena + wid * 256;           // [4][64] per wave
  float* hsd = arena + 1024 + wid * 256;   // [4][64] per wave
#pragma unroll
  for (int n = 0; n < 4; ++n) es[n * 64 + lane] = p.encA[(size_t)(bv0 + n) * 64 + lane];
  float hj[4], uj[4];
#pragma unroll
  for (int n = 0; n < 4; ++n) { hj[n] = p.db1[lane]; uj[n] = p.ub1[lane]; }
  for (int f = 0; f < 64; ++f) {
    float a = p.dw1[f * 64 + lane], c = p.uw1[f * 64 + lane];
#pragma unroll
    for (int n = 0; n < 4; ++n) {
      hj[n] += es[n * 64 + f] * a;
      uj[n] += es[n * 64 + f] * c;
    }
  }
  float w2v = p.uw2[lane];
#pragma unroll
  for (int n = 0; n < 4; ++n) {
    hsd[n * 64 + lane] = hj[n];  // NO relu: decoder is linear
    float s = wave_sum(uj[n] * w2v);
    if (lane == 0) p.dvp[bv0 + n] = s + p.ub2[0];
  }
  for (int n = 0; n < 4; ++n) {
    int v = v0 + n;
    int dvv = p.deg[v];
    int w = (lane < dvv) ? p.nbr[v * CAP + lane] : 0;
    const float4* wrow = (const float4*)(p.w2t + w * 64);
    const float4* hv4 = (const float4*)(hsd + n * 64);
    float d = 0.f;
#pragma unroll
    for (int f = 0; f < 16; ++f) {
      float4 wv = wrow[f];
      float4 hv = hv4[f];  // LDS broadcast
      d += hv.x * wv.x + hv.y * wv.y + hv.z * wv.z + hv.w * wv.w;
    }
    d += p.dec_b2[w];
    float pp = d * d;
    float myp = (lane < dvv) ? pp : -1e30f;
    float m = wave_max(myp);
    float e = (lane < dvv) ? __expf(myp - m) : 0.f;
    float s = wave_sum(e);
    float coef = e / s;
    if (lane < dvv) {
      int idx = p.csc_pos[v * CAP + lane];
      p.fwe[(size_t)b * MAXNNZ + idx] = coef;
      p.meta[idx] = (unsigned)v | ((unsigned)w << 16);
    }
    float r = wave_sum(coef * coef);
    if (lane == 0) p.rssq[bv0 + n] = r;
  }
}

// ---- L5: flow iterations (register-cached edges, LDS scatter) + dual + final ----
__global__ __launch_bounds__(1024) void flow_dual_kernel(
    const float* __restrict__ fwe, const unsigned* __restrict__ meta,
    const float* __restrict__ rssq, const float* __restrict__ dv,
    const float* __restrict__ demands, const int* __restrict__ nbr_out,
    const int* __restrict__ deg_out, float* __restrict__ partial,
    unsigned* __restrict__ done, float* __restrict__ out) {
  int b = blockIdx.x;
  int v = threadIdx.x;  // 1024
  __shared__ float o[V], infl[V], dvs[V];
  __shared__ float red[16];
  float dem = demands[b * V + v];
  dvs[v] = dv[b * V + v];
  o[v] = fmaxf(-dem, 0.f);  // o_1 = relu(-demand)
  infl[v] = 0.f;
  const float4* fp = (const float4*)(fwe + (size_t)b * MAXNNZ + v * SE);
  const uint4* mp = (const uint4*)(meta + v * SE);
  float fr[SE];
  unsigned mr[SE];
#pragma unroll
  for (int i = 0; i < SE / 4; ++i) {
    float4 f4 = fp[i];
    uint4 m4 = mp[i];
    fr[4 * i + 0] = f4.x; fr[4 * i + 1] = f4.y; fr[4 * i + 2] = f4.z; fr[4 * i + 3] = f4.w;
    mr[4 * i + 0] = m4.x; mr[4 * i + 1] = m4.y; mr[4 * i + 2] = m4.z; mr[4 * i + 3] = m4.w;
  }
  __syncthreads();
  for (int it = 0; it < 9; ++it) {
    float acc = 0.f;
    int pdst = -1;
#pragma unroll
    for (int i = 0; i < SE; ++i) {
      int src = mr[i] & 0xFFFF;
      int dst = mr[i] >> 16;
      if (dst != pdst) {
        if (acc != 0.f) atomicAdd(&infl[pdst], acc);
        acc = 0.f;
        pdst = dst;
      }
      acc += fr[i] * o[src];
    }
    if (acc != 0.f) atomicAdd(&infl[pdst], acc);
    __syncthreads();
    float nv = fmaxf(infl[v] - dem, 0.f);
    o[v] = nv;
    infl[v] = 0.f;
    __syncthreads();
  }
  float o10 = o[v];
  float local = o10 * o10 * rssq[b * V + v];
  float dvv = dvs[v];
  int dout = deg_out[v];
  float acc = 0.f;
  for (int k = 0; k < dout; ++k) {
    float diff = dvv - dvs[nbr_out[v * CAP + k]];
    if (diff > 0.f) acc += diff * diff;
  }
  local += 0.25f * acc + dvv * dem;
  local = wave_sum(local);
  if ((v & 63) == 0) red[v >> 6] = local;
  __syncthreads();
  if (v < 16) {
    float r = red[v];
    for (int o2 = 8; o2 > 0; o2 >>= 1) r += __shfl_xor(r, o2, 16);
    if (v == 0) {
      __hip_atomic_store(&partial[b], r, __ATOMIC_RELEASE, __HIP_MEMORY_SCOPE_AGENT);
      unsigned old = __hip_atomic_fetch_add(done, 1u, __ATOMIC_ACQ_REL, __HIP_MEMORY_SCOPE_AGENT);
      if (old == B - 1) {  // last block: deterministic fixed-order sum
        float s = 0.f;
        for (int i = 0; i < B; ++i)
          s += __hip_atomic_load(&partial[i], __ATOMIC_ACQUIRE, __HIP_MEMORY_SCOPE_AGENT);
        out[0] = s * (1.0f / B);
      }
    }
  }
}

extern "C" void kernel_launch(void* const* d_in, const int* in_sizes, int n_in,
                              void* d_out, int out_size, void* d_ws, size_t ws_size,
                              hipStream_t stream) {
  Params P;
  P.adj     = (const float*)d_in[2];
  P.demands = (const float*)d_in[0];
  P.emb     = (const float*)d_in[1];
  P.ew1 = (const float*)d_in[3];  P.eb1 = (const float*)d_in[4];
  P.ew2 = (const float*)d_in[5];  P.eb2 = (const float*)d_in[6];
  P.gat_w = (const float*)d_in[7];
  P.ga1 = (const float*)d_in[8];  P.ga2 = (const float*)d_in[9];
  P.gate_w = (const float*)d_in[10]; P.gate_u = (const float*)d_in[11];
  P.gate_b = (const float*)d_in[12];
  P.dw1 = (const float*)d_in[13]; P.db1 = (const float*)d_in[14];
  P.dec_w2 = (const float*)d_in[15]; P.dec_b2 = (const float*)d_in[16];
  P.uw1 = (const float*)d_in[17]; P.ub1 = (const float*)d_in[18];
  P.uw2 = (const float*)d_in[19]; P.ub2 = (const float*)d_in[20];

  char* pz = (char*)d_ws;
  P.deg_in   = (int*)pz;                    // 4096 B (zeroed by init_kernel)
  P.slot_cur = (int*)(pz + 4096);           // 4096 B (zeroed by init_kernel)
  unsigned* done = (unsigned*)(pz + 8192);  // 4 B   (zeroed by init_kernel)
  char* p = pz + 8448;
  auto alloc = [&](size_t n) { void* r = (void*)p; p += (n + 255) & ~(size_t)255; return r; };
  P.nbr     = (int*)alloc((size_t)V * CAP * 4);
  P.deg     = (int*)alloc((size_t)V * 4);
  P.csc_pos = (int*)alloc((size_t)V * CAP * 4);
  P.fwe     = (float*)alloc((size_t)B * MAXNNZ * 4);
  P.meta    = (unsigned*)alloc((size_t)MAXNNZ * 4);
  P.w2t     = (float*)alloc((size_t)64 * V * 4);
  P.wa1     = (float*)alloc((size_t)H * 64 * 4);
  P.wa2     = (float*)alloc((size_t)H * 64 * 4);
  P.encA    = (float*)alloc((size_t)B * V * 64 * 4);
  P.encB    = (float*)alloc((size_t)B * V * 64 * 4);
  P.ssA     = (float*)alloc((size_t)B * H * V * 4);
  P.snA     = (float*)alloc((size_t)B * H * V * 4);
  P.ssB     = (float*)alloc((size_t)B * H * V * 4);
  P.snB     = (float*)alloc((size_t)B * H * V * 4);
  P.dvp     = (float*)alloc((size_t)B * V * 4);
  P.rssq    = (float*)alloc((size_t)B * V * 4);
  float* partial = (float*)alloc((size_t)B * 4);

  init_kernel<<<9, 256, 0, stream>>>(P.deg_in, P.slot_cur, done, P.gat_w, P.ga1, P.ga2,
                                     P.wa1, P.wa2);
  p0_kernel<<<NBLK, NTHR, 0, stream>>>(P);
  p1_kernel<<<NBLK, NTHR, 0, stream>>>(P);
  p2_kernel<<<NBLK, NTHR, 0, stream>>>(P);
  p3_kernel<<<NBLK, NTHR, 0, stream>>>(P);
  flow_dual_kernel<<<B, 1024, 0, stream>>>(P.fwe, P.meta, P.rssq, P.dvp, P.demands,
                                           P.nbr, P.deg, partial, done, (float*)d_out);
}

// Round 14
// 147.894 us; speedup vs baseline: 1.5557x; 1.5557x over previous
//
#include <hip/hip_runtime.h>
#include <math.h>

#define B 8
#define V 1024
#define E 32
#define H 4
#define CAP 64        // max out-degree capacity; E[deg]=17, P(deg>64) ~ 1e-21
#define MAXNNZ 20480  // nnz ~ 17390 +/- 128; +24 sigma headroom
#define SE (MAXNNZ / V)  // 20 edges per thread in flow kernel
#define ZBLK 128      // zero-role blocks in setup kernel

// XCD-aware decode: blockIdx round-robins across 8 XCDs on MI355X, and B==8.
// b = blockIdx & 7 pins each batch to one XCD -> per-XCD working set fits 4MB L2.

__device__ __forceinline__ float wave_sum(float v) {
  for (int o = 32; o > 0; o >>= 1) v += __shfl_xor(v, o);
  return v;
}
__device__ __forceinline__ float wave_max(float v) {
  for (int o = 32; o > 0; o >>= 1) v = fmaxf(v, __shfl_xor(v, o));
  return v;
}

// ---- L0: zero deg_in/slot_cur/done + precompute wa1/wa2 = gat_w @ a1/a2 ----
__global__ void zero_wa_kernel(int* __restrict__ deg_in, int* __restrict__ slot_cur,
                               unsigned* __restrict__ done, const float* __restrict__ gat_w,
                               const float* __restrict__ a1, const float* __restrict__ a2,
                               float* __restrict__ wa1, float* __restrict__ wa2) {
  int blk = blockIdx.x, tid = threadIdx.x;
  if (blk < 4) {
    deg_in[blk * 256 + tid] = 0;
  } else if (blk < 8) {
    slot_cur[(blk - 4) * 256 + tid] = 0;
  } else {
    if (tid == 0) *done = 0u;
    int h = tid >> 6, f = tid & 63;
    float s1 = 0.f, s2 = 0.f;
    const float* W = gat_w + h * 4096 + f * 64;
    for (int g = 0; g < 64; ++g) {
      float w = W[g];
      s1 += w * a1[h * 64 + g];
      s2 += w * a2[h * 64 + g];
    }
    wa1[h * 64 + f] = s1;
    wa2[h * 64 + f] = s2;
  }
}

// ---- L1: merged setup (64-thread blocks, role by blockIdx) — R9 verbatim ----
// roles: [0,V) build_csr + atomic in-degree; [V,2V) encoder MLP + layer-1 scores;
//        [2V,3V) transpose dec_w2; [3V,3V+ZBLK) zero fwe+meta.
#define ENV 8
__global__ void setup_kernel(const float* __restrict__ adj, const float* __restrict__ demands,
                             const float* __restrict__ emb,
                             const float* __restrict__ ew1, const float* __restrict__ eb1,
                             const float* __restrict__ ew2, const float* __restrict__ eb2,
                             const float* __restrict__ dec_w2,
                             const float* __restrict__ wa1, const float* __restrict__ wa2,
                             int* __restrict__ nbr, int* __restrict__ deg,
                             int* __restrict__ deg_in, float* __restrict__ enc,
                             float* __restrict__ ss, float* __restrict__ sn,
                             float* __restrict__ w2t, float* __restrict__ fwe,
                             unsigned int* __restrict__ meta) {
  int blk = blockIdx.x;
  int j = threadIdx.x;  // 64
  if (blk < V) {
    int v = blk;
    int base = 0;
    for (int c = 0; c < V; c += 64) {
      float a = adj[v * V + c + j];
      unsigned long long m = __ballot(a > 0.5f);
      int pos = __popcll(m & ((1ull << j) - 1ull));
      if (a > 0.5f && base + pos < CAP) {
        nbr[v * CAP + base + pos] = c + j;
        atomicAdd(&deg_in[c + j], 1);
      }
      base += __popcll(m);
    }
    if (j == 0) deg[v] = (base < CAP) ? base : CAP;
  } else if (blk < 2 * V) {
    int eb = blk - V;
    int b = eb & 7;
    int v0 = (eb >> 3) * ENV;
    int bv0 = b * V + v0;
    __shared__ float xs[ENV][E + 1];
    __shared__ float hs[ENV][64];
#pragma unroll
    for (int n = 0; n < ENV; ++n) {
      if (j < E) xs[n][j] = emb[(v0 + n) * E + j];
      else if (j == E) xs[n][E] = demands[b * V + v0 + n];
    }
    __syncthreads();
    float h[ENV];
#pragma unroll
    for (int n = 0; n < ENV; ++n) h[n] = eb1[j];
    for (int i = 0; i < E + 1; ++i) {
      float wv = ew1[i * 64 + j];
#pragma unroll
      for (int n = 0; n < ENV; ++n) h[n] += xs[n][i] * wv;
    }
#pragma unroll
    for (int n = 0; n < ENV; ++n) hs[n][j] = fmaxf(h[n], 0.f);
    __syncthreads();
    float o[ENV];
#pragma unroll
    for (int n = 0; n < ENV; ++n) o[n] = eb2[j];
    for (int i = 0; i < 64; ++i) {
      float wv = ew2[i * 64 + j];
#pragma unroll
      for (int n = 0; n < ENV; ++n) o[n] += hs[n][i] * wv;
    }
#pragma unroll
    for (int n = 0; n < ENV; ++n) {
      o[n] = fmaxf(o[n], 0.f);
      enc[(bv0 + n) * 64 + j] = o[n];
    }
#pragma unroll
    for (int n = 0; n < ENV; ++n) {
#pragma unroll
      for (int hh = 0; hh < H; ++hh) {
        float v1 = wave_sum(o[n] * wa1[hh * 64 + j]);
        float v2 = wave_sum(o[n] * wa2[hh * 64 + j]);
        if (j == 0) {
          ss[(b * H + hh) * V + v0 + n] = v1;
          sn[(b * H + hh) * V + v0 + n] = v2;
        }
      }
    }
  } else if (blk < 3 * V) {
    int w = blk - 2 * V;
    w2t[w * 64 + j] = dec_w2[j * V + w];
  } else {
    int idx = (blk - 3 * V) * 64 + j;
    for (int i = idx; i < B * MAXNNZ; i += ZBLK * 64) fwe[i] = 0.f;
    for (int i = idx; i < MAXNNZ; i += ZBLK * 64) meta[i] = 0u;
  }
}

// ---- L2/L3: GAT layer (aggregate-then-project, R9 grid: 1024 blocks x 256) ----
// do_csc tail runs ONLY for b==0 blocks (each v-group exactly once — the R13
// bug was running it 8x, once per batch, corrupting slot_cur/csc_pos).
#define GNV 8
__global__ __launch_bounds__(256) void gat2_kernel(
    const float* __restrict__ enc_in, const float* __restrict__ ss_in,
    const float* __restrict__ sn_in, const int* __restrict__ nbr,
    const int* __restrict__ deg, const float* __restrict__ gat_w,
    const float* __restrict__ gate_w, const float* __restrict__ gate_u,
    const float* __restrict__ gate_b, const float* __restrict__ wa1,
    const float* __restrict__ wa2, float* __restrict__ enc_out,
    float* __restrict__ ss_out, float* __restrict__ sn_out, int write_s,
    const int* __restrict__ deg_in, int* __restrict__ slot_cur,
    int* __restrict__ csc_pos, int do_csc) {
  int b = blockIdx.x & 7;
  int v0 = (blockIdx.x >> 3) * GNV;
  int tid = threadIdx.x;  // 256
  int wid = tid >> 6, lane = tid & 63;
  __shared__ float agg[GNV][H][64];   // 8 KB
  __shared__ float gpart[GNV][4][64]; // 8 KB
  __shared__ float nxts[GNV][64];     // 2 KB
  __shared__ float encs[GNV][64];     // 2 KB
  __shared__ int ioff[V];             // 4 KB (csc tail)
  const float* eb = enc_in + (size_t)b * V * 64;
  for (int i = tid; i < GNV * 64; i += 256) encs[i >> 6][i & 63] = eb[v0 * 64 + i];
  for (int n = wid; n < GNV; n += 4) {
    int v = v0 + n;
    int dvv = deg[v];
    int wk = (lane < dvv) ? nbr[v * CAP + lane] : 0;
    float c[H];
#pragma unroll
    for (int h = 0; h < H; ++h) {
      float x = ss_in[(b * H + h) * V + v] + sn_in[(b * H + h) * V + wk];
      x = (x > 0.f) ? x : 0.2f * x;  // leaky_relu 0.2
      if (lane >= dvv) x = -1e30f;
      float m = wave_max(x);
      float e = (lane < dvv) ? __expf(x - m) : 0.f;
      float s = wave_sum(e);
      c[h] = e / s;
    }
    float a0 = 0.f, a1v = 0.f, a2v = 0.f, a3v = 0.f;
    for (int k = 0; k < dvv; ++k) {
      int w = __shfl(wk, k);
      float ev = eb[w * 64 + lane];  // one 256B gather serves all 4 heads
      a0 += __shfl(c[0], k) * ev;
      a1v += __shfl(c[1], k) * ev;
      a2v += __shfl(c[2], k) * ev;
      a3v += __shfl(c[3], k) * ev;
    }
    agg[n][0][lane] = a0;
    agg[n][1][lane] = a1v;
    agg[n][2][lane] = a2v;
    agg[n][3][lane] = a3v;
  }
  __syncthreads();
  {
    const float* W = gat_w + wid * 4096;
    float hv[GNV];
#pragma unroll
    for (int n = 0; n < GNV; ++n) hv[n] = 0.f;
    for (int f = 0; f < 64; ++f) {
      float wf = W[f * 64 + lane];
#pragma unroll
      for (int n = 0; n < GNV; ++n) hv[n] += agg[n][wid][f] * wf;
    }
#pragma unroll
    for (int n = 0; n < GNV; ++n) gpart[n][wid][lane] = hv[n];
  }
  __syncthreads();
  for (int i = tid; i < GNV * 64; i += 256) {
    int n = i >> 6, g = i & 63;
    float s4 = gpart[n][0][g] + gpart[n][1][g] + gpart[n][2][g] + gpart[n][3][g];
    nxts[n][g] = fmaxf(0.25f * s4, 0.f);
  }
  __syncthreads();
  {
    float part[GNV];
#pragma unroll
    for (int n = 0; n < GNV; ++n) part[n] = 0.f;
    for (int f = wid * 16; f < wid * 16 + 16; ++f) {
      float gw = gate_w[f * 64 + lane], gu = gate_u[f * 64 + lane];
#pragma unroll
      for (int n = 0; n < GNV; ++n) part[n] += nxts[n][f] * gw + encs[n][f] * gu;
    }
    __syncthreads();
#pragma unroll
    for (int n = 0; n < GNV; ++n) gpart[n][wid][lane] = part[n];
  }
  __syncthreads();
  for (int i = tid; i < GNV * 64; i += 256) {
    int n = i >> 6, g = i & 63;
    float zs = gpart[n][0][g] + gpart[n][1][g] + gpart[n][2][g] + gpart[n][3][g] + gate_b[g];
    float z = 1.f / (1.f + __expf(-zs));
    float out = z * nxts[n][g] + (1.f - z) * encs[n][g];
    encs[n][g] = out;  // reuse as output buffer
    enc_out[((size_t)b * V + v0 + n) * 64 + g] = out;
  }
  if (write_s) {
    __syncthreads();
    float w1v = wa1[wid * 64 + lane], w2v = wa2[wid * 64 + lane];
#pragma unroll
    for (int n = 0; n < GNV; ++n) {
      float e = encs[n][lane];
      float ssv = wave_sum(e * w1v);
      float snv = wave_sum(e * w2v);
      if (lane == 0) {
        ss_out[(b * H + wid) * V + v0 + n] = ssv;
        sn_out[(b * H + wid) * V + v0 + n] = snv;
      }
    }
  }
  if (do_csc && b == 0) {  // exactly once per v-group (R13 bug: ran 8x)
    __syncthreads();
    if (tid < 64) {  // redundant per-block exclusive scan of pristine deg_in
      int vals[16];
      int tot = 0;
#pragma unroll
      for (int i = 0; i < 16; ++i) {
        vals[i] = tot;
        tot += deg_in[tid * 16 + i];
      }
      int run = tot;
      for (int o = 1; o < 64; o <<= 1) {
        int u = __shfl_up(run, o);
        if (lane >= o) run += u;
      }
      int excl = run - tot;
#pragma unroll
      for (int i = 0; i < 16; ++i) ioff[tid * 16 + i] = excl + vals[i];
    }
    __syncthreads();
    for (int n = wid; n < GNV; n += 4) {
      int v = v0 + n;
      if (lane < deg[v]) {
        int w = nbr[v * CAP + lane];
        csc_pos[v * CAP + lane] = ioff[w] + atomicAdd(&slot_cur[w], 1);
      }
    }
  }
}

// ---- L4: fused decoder+dual+flow-weights (R8-verified: 4 nodes/block,
//      1 wave/node, lane-per-edge fw — no serial per-edge reductions) ----
#define DNV 4
__global__ __launch_bounds__(256) void decfw_kernel(
    const float* __restrict__ enc, const float* __restrict__ dw1,
    const float* __restrict__ db1, const float* __restrict__ uw1,
    const float* __restrict__ ub1, const float* __restrict__ uw2,
    const float* __restrict__ ub2, const float* __restrict__ w2t,
    const float* __restrict__ dec_b2, const int* __restrict__ nbr,
    const int* __restrict__ deg, const int* __restrict__ csc_pos,
    float* __restrict__ fwe, unsigned int* __restrict__ meta,
    float* __restrict__ rssq, float* __restrict__ dvout) {
  int b = blockIdx.x & 7;
  int v0 = (blockIdx.x >> 3) * DNV;
  int bv0 = b * V + v0;
  int tid = threadIdx.x;  // 256
  int wv = tid >> 6, j = tid & 63;
  __shared__ float es[DNV][64];
  __shared__ float hs[DNV][64];
  es[wv][j] = enc[(bv0 + wv) * 64 + j];
  __syncthreads();
  float hj = db1[j], uj = ub1[j];
  for (int f = 0; f < 64; ++f) {
    hj += es[wv][f] * dw1[f * 64 + j];
    uj += es[wv][f] * uw1[f * 64 + j];
  }
  hs[wv][j] = hj;  // NO relu: decoder is linear
  float sdv = wave_sum(uj * uw2[j]);
  if (j == 0) dvout[bv0 + wv] = sdv + ub2[0];
  __syncthreads();
  int v = v0 + wv;
  int dvv = deg[v];
  int w = (j < dvv) ? nbr[v * CAP + j] : 0;
  const float4* wrow = (const float4*)(w2t + w * 64);
  const float4* hv4 = (const float4*)hs[wv];
  float d = 0.f;
#pragma unroll
  for (int f = 0; f < 16; ++f) {
    float4 wvv = wrow[f];
    float4 hv = hv4[f];  // LDS broadcast
    d += hv.x * wvv.x + hv.y * wvv.y + hv.z * wvv.z + hv.w * wvv.w;
  }
  d += dec_b2[w];
  float pp = d * d;
  float myp = (j < dvv) ? pp : -1e30f;
  float m = wave_max(myp);
  float e = (j < dvv) ? __expf(myp - m) : 0.f;
  float s = wave_sum(e);
  float coef = e / s;
  if (j < dvv) {
    int idx = csc_pos[v * CAP + j];
    fwe[(size_t)b * MAXNNZ + idx] = coef;
    meta[idx] = (unsigned)v | ((unsigned)w << 16);
  }
  float r = wave_sum(coef * coef);
  if (j == 0) rssq[bv0 + wv] = r;
}

// ---- L5: flow iterations (register-cached edges, LDS scatter) + dual + final ----
__global__ __launch_bounds__(1024) void flow_dual_kernel(
    const float* __restrict__ fwe, const unsigned* __restrict__ meta,
    const float* __restrict__ rssq, const float* __restrict__ dv,
    const float* __restrict__ demands, const int* __restrict__ nbr_out,
    const int* __restrict__ deg_out, float* __restrict__ partial,
    unsigned* __restrict__ done, float* __restrict__ out) {
  int b = blockIdx.x;
  int v = threadIdx.x;  // 1024
  __shared__ float o[V], infl[V], dvs[V];
  __shared__ float red[16];
  float dem = demands[b * V + v];
  dvs[v] = dv[b * V + v];
  o[v] = fmaxf(-dem, 0.f);  // o_1 = relu(-demand)
  infl[v] = 0.f;
  const float4* fp = (const float4*)(fwe + (size_t)b * MAXNNZ + v * SE);
  const uint4* mp = (const uint4*)(meta + v * SE);
  float fr[SE];
  unsigned mr[SE];
#pragma unroll
  for (int i = 0; i < SE / 4; ++i) {
    float4 f4 = fp[i];
    uint4 m4 = mp[i];
    fr[4 * i + 0] = f4.x; fr[4 * i + 1] = f4.y; fr[4 * i + 2] = f4.z; fr[4 * i + 3] = f4.w;
    mr[4 * i + 0] = m4.x; mr[4 * i + 1] = m4.y; mr[4 * i + 2] = m4.z; mr[4 * i + 3] = m4.w;
  }
  __syncthreads();
  for (int it = 0; it < 9; ++it) {
    float acc = 0.f;
    int pdst = -1;
#pragma unroll
    for (int i = 0; i < SE; ++i) {
      int src = mr[i] & 0xFFFF;
      int dst = mr[i] >> 16;
      if (dst != pdst) {
        if (acc != 0.f) atomicAdd(&infl[pdst], acc);
        acc = 0.f;
        pdst = dst;
      }
      acc += fr[i] * o[src];
    }
    if (acc != 0.f) atomicAdd(&infl[pdst], acc);
    __syncthreads();
    float nv = fmaxf(infl[v] - dem, 0.f);
    o[v] = nv;
    infl[v] = 0.f;
    __syncthreads();
  }
  float o10 = o[v];
  float local = o10 * o10 * rssq[b * V + v];
  float dvv = dvs[v];
  int dout = deg_out[v];
  float acc = 0.f;
  for (int k = 0; k < dout; ++k) {
    float diff = dvv - dvs[nbr_out[v * CAP + k]];
    if (diff > 0.f) acc += diff * diff;
  }
  local += 0.25f * acc + dvv * dem;
  local = wave_sum(local);
  if ((v & 63) == 0) red[v >> 6] = local;
  __syncthreads();
  if (v < 16) {
    float r = red[v];
    for (int o2 = 8; o2 > 0; o2 >>= 1) r += __shfl_xor(r, o2, 16);
    if (v == 0) {
      __hip_atomic_store(&partial[b], r, __ATOMIC_RELEASE, __HIP_MEMORY_SCOPE_AGENT);
      unsigned old = __hip_atomic_fetch_add(done, 1u, __ATOMIC_ACQ_REL, __HIP_MEMORY_SCOPE_AGENT);
      if (old == B - 1) {  // last block: deterministic fixed-order sum
        float s = 0.f;
        for (int i = 0; i < B; ++i)
          s += __hip_atomic_load(&partial[i], __ATOMIC_ACQUIRE, __HIP_MEMORY_SCOPE_AGENT);
        out[0] = s * (1.0f / B);
      }
    }
  }
}

extern "C" void kernel_launch(void* const* d_in, const int* in_sizes, int n_in,
                              void* d_out, int out_size, void* d_ws, size_t ws_size,
                              hipStream_t stream) {
  const float* demands = (const float*)d_in[0];
  const float* emb     = (const float*)d_in[1];
  const float* adj     = (const float*)d_in[2];
  const float* enc_w1  = (const float*)d_in[3];
  const float* enc_b1  = (const float*)d_in[4];
  const float* enc_w2  = (const float*)d_in[5];
  const float* enc_b2  = (const float*)d_in[6];
  const float* gat_w   = (const float*)d_in[7];
  const float* gat_a1  = (const float*)d_in[8];
  const float* gat_a2  = (const float*)d_in[9];
  const float* gate_w  = (const float*)d_in[10];
  const float* gate_u  = (const float*)d_in[11];
  const float* gate_b  = (const float*)d_in[12];
  const float* dec_w1  = (const float*)d_in[13];
  const float* dec_b1  = (const float*)d_in[14];
  const float* dec_w2  = (const float*)d_in[15];
  const float* dec_b2  = (const float*)d_in[16];
  const float* dual_w1 = (const float*)d_in[17];
  const float* dual_b1 = (const float*)d_in[18];
  const float* dual_w2 = (const float*)d_in[19];
  const float* dual_b2 = (const float*)d_in[20];

  char* pz = (char*)d_ws;
  int* deg_in   = (int*)pz;                 // 4096 B (zeroed by zero_wa)
  int* slot_cur = (int*)(pz + 4096);        // 4096 B (zeroed by zero_wa)
  unsigned* done = (unsigned*)(pz + 8192);  // 4 B    (zeroed by zero_wa)
  char* p = pz + 8448;
  auto alloc = [&](size_t n) { void* r = (void*)p; p += (n + 255) & ~(size_t)255; return r; };
  int* nbr_out   = (int*)alloc((size_t)V * CAP * 4);
  int* deg_out   = (int*)alloc((size_t)V * 4);
  int* csc_pos   = (int*)alloc((size_t)V * CAP * 4);
  float* fwe     = (float*)alloc((size_t)B * MAXNNZ * 4);
  unsigned int* meta = (unsigned int*)alloc((size_t)MAXNNZ * 4);
  float* w2t     = (float*)alloc((size_t)64 * V * 4);
  float* wa1     = (float*)alloc((size_t)H * 64 * 4);
  float* wa2     = (float*)alloc((size_t)H * 64 * 4);
  float* encA    = (float*)alloc((size_t)B * V * 64 * 4);
  float* encB    = (float*)alloc((size_t)B * V * 64 * 4);
  float* ssA     = (float*)alloc((size_t)B * H * V * 4);
  float* snA     = (float*)alloc((size_t)B * H * V * 4);
  float* ssB     = (float*)alloc((size_t)B * H * V * 4);
  float* snB     = (float*)alloc((size_t)B * H * V * 4);
  float* dv      = (float*)alloc((size_t)B * V * 4);
  float* rssq    = (float*)alloc((size_t)B * V * 4);
  float* partial = (float*)alloc((size_t)B * 4);

  zero_wa_kernel<<<9, 256, 0, stream>>>(deg_in, slot_cur, done, gat_w, gat_a1, gat_a2,
                                        wa1, wa2);
  setup_kernel<<<3 * V + ZBLK, 64, 0, stream>>>(
      adj, demands, emb, enc_w1, enc_b1, enc_w2, enc_b2, dec_w2, wa1, wa2,
      nbr_out, deg_out, deg_in, encA, ssA, snA, w2t, fwe, meta);
  gat2_kernel<<<B * V / GNV, 256, 0, stream>>>(encA, ssA, snA, nbr_out, deg_out, gat_w,
                                               gate_w, gate_u, gate_b, wa1, wa2,
                                               encB, ssB, snB, 1,
                                               deg_in, slot_cur, csc_pos, 1);
  gat2_kernel<<<B * V / GNV, 256, 0, stream>>>(encB, ssB, snB, nbr_out, deg_out, gat_w,
                                               gate_w, gate_u, gate_b, wa1, wa2,
                                               encA, ssA, snA, 0,
                                               deg_in, slot_cur, csc_pos, 0);
  decfw_kernel<<<B * V / DNV, 256, 0, stream>>>(encA, dec_w1, dec_b1, dual_w1, dual_b1,
                                                dual_w2, dual_b2, w2t, dec_b2, nbr_out,
                                                deg_out, csc_pos, fwe, meta, rssq, dv);
  flow_dual_kernel<<<B, 1024, 0, stream>>>(fwe, meta, rssq, dv, demands, nbr_out, deg_out,
                                           partial, done, (float*)d_out);
}